// Round 1
// baseline (572.985 us; speedup 1.0000x reference)
//
#include <hip/hip_runtime.h>
#include <hip/hip_bf16.h>

// Problem: out[b,s,o] = sum_i x[b,s,i]*W[o,i] + bias[o] + sum_r (sum_i x[b,s,i]*A[r,i]) * B[o,r]
// Fused as: W' = W + B@A (bf16), xb = bf16(x), out = xb @ W'^T + bias  (fp32 out)
// M = 8192, N = 4096, K = 4096.

#define M_TOT 8192
#define NDIM  4096
#define KDIM  4096
#define RANK  16

#define BM 128
#define BN 128
#define BK 64

typedef float f4 __attribute__((ext_vector_type(4)));
typedef short s8v __attribute__((ext_vector_type(8)));   // 8 bf16 payloads (4 VGPRs)

// ---------- helpers ----------

static __device__ __forceinline__ unsigned short f2bf(float f) {
  union { float f; unsigned u; } v; v.f = f;
  unsigned r = v.u + 0x7FFF + ((v.u >> 16) & 1);   // round-to-nearest-even
  return (unsigned short)(r >> 16);
}
static __device__ __forceinline__ unsigned pack2(float lo, float hi) {
  return (unsigned)f2bf(lo) | ((unsigned)f2bf(hi) << 16);
}

// MFMA via inline asm: avoids builtin signature (short8 vs __bf16x8) ambiguity.
// D(f32x4) = A(16x32 bf16) * B(32x16 bf16) + D
static __device__ __forceinline__ void mfma_16x16x32_bf16(f4& d, s8v a, s8v b) {
  asm volatile("v_mfma_f32_16x16x32_bf16 %0, %1, %2, %0"
               : "+v"(d) : "v"(a), "v"(b));
}

#define GLOAD_LDS16(gaddr, laddr)                                              \
  __builtin_amdgcn_global_load_lds(                                            \
      (__attribute__((address_space(1))) void*)(gaddr),                        \
      (__attribute__((address_space(3))) void*)(laddr), 16, 0, 0)

// ---------- kernel 1: cast x (fp32 -> bf16 bits), vectorized 8/thread ----------

__global__ __launch_bounds__(256) void cast_x_kernel(
    const float* __restrict__ in, unsigned short* __restrict__ out, int n8) {
  int i = blockIdx.x * blockDim.x + threadIdx.x;
  int stride = gridDim.x * blockDim.x;
  for (; i < n8; i += stride) {
    const float4* p = (const float4*)in + (size_t)i * 2;
    float4 a = p[0];
    float4 b = p[1];
    uint4 o;
    o.x = pack2(a.x, a.y);
    o.y = pack2(a.z, a.w);
    o.z = pack2(b.x, b.y);
    o.w = pack2(b.z, b.w);
    ((uint4*)out)[i] = o;
  }
}

// ---------- kernel 2: W' = W + B@A, cast to bf16 ----------
// Thread owns 4 consecutive i; caches A[0..16][i..i+4) in 64 VGPRs; loops 64 o-rows.

__global__ __launch_bounds__(256) void fuse_w_kernel(
    const float* __restrict__ W, const float* __restrict__ A,
    const float* __restrict__ B, unsigned short* __restrict__ Wb) {
  const int t = threadIdx.x;
  const int i = blockIdx.x * 1024 + t * 4;
  const int o0 = blockIdx.y * 64;

  f4 areg[RANK];
#pragma unroll
  for (int r = 0; r < RANK; ++r)
    areg[r] = *(const f4*)(A + (size_t)r * KDIM + i);

  for (int o = o0; o < o0 + 64; ++o) {
    f4 acc = *(const f4*)(W + (size_t)o * KDIM + i);
#pragma unroll
    for (int r = 0; r < RANK; ++r) {
      float br = B[o * RANK + r];   // o uniform -> scalar load
      acc += br * areg[r];
    }
    uint2 pk;
    pk.x = pack2(acc.x, acc.y);
    pk.y = pack2(acc.z, acc.w);
    *(uint2*)(Wb + (size_t)o * KDIM + i) = pk;
  }
}

// ---------- kernel 3: bf16 GEMM, C[m][n] = sum_k Xb[m][k]*Wb[n][k] + bias[n] ----------
// m97-structure: 128x128 tile, BK=64, 4 waves (2x2) x 64x64 out, 4x4 frags of 16x16,
// global_load_lds width=16 staging, single LDS buffer, 2 barriers per K-step.

__global__ __launch_bounds__(256, 2) void gemm_kernel(
    const unsigned short* __restrict__ Xb,   // [M][K] bf16 bits
    const unsigned short* __restrict__ Wb,   // [N][K] bf16 bits
    const float* __restrict__ bias,
    float* __restrict__ C) {
  __shared__ __attribute__((aligned(16))) unsigned short As[BM * BK];  // 16 KB
  __shared__ __attribute__((aligned(16))) unsigned short Bs[BN * BK];  // 16 KB

  const int tid  = threadIdx.x;
  const int wave = tid >> 6;
  const int lane = tid & 63;

  const int brow = blockIdx.y * BM;
  const int bcol = blockIdx.x * BN;

  // Staging geometry: thread stages 16B; tile elem offset = j*2048 + wave*512 + lane*8
  // -> row = j*32 + wave*8 + (lane>>3), col = (lane&7)*8. LDS dest is linear in lane
  // (wave-uniform base + lane*16B) as global_load_lds requires.
  const int srow = wave * 8 + (lane >> 3);
  const int scol = (lane & 7) * 8;

  const unsigned short* gA = Xb + (size_t)(brow + srow) * KDIM + scol;
  const unsigned short* gB = Wb + (size_t)(bcol + srow) * KDIM + scol;
  unsigned short* lA = &As[srow * BK + scol];
  unsigned short* lB = &Bs[srow * BK + scol];

  // Wave 2x2 -> 64x64 sub-tile; frag coords per m89/m91 layout.
  const int wrow = (wave >> 1) * 64;
  const int wcol = (wave & 1) * 64;
  const int fr = lane & 15;   // A: row within 16; B: col within 16; C: col
  const int fq = lane >> 4;   // k-group; C: row-quad

  const unsigned short* rA = &As[(wrow + fr) * BK + fq * 8];
  const unsigned short* rB = &Bs[(wcol + fr) * BK + fq * 8];

  f4 acc[4][4] = {};

  for (int k0 = 0; k0 < KDIM; k0 += BK) {
#pragma unroll
    for (int j = 0; j < 4; ++j)
      GLOAD_LDS16(gA + (size_t)j * 32 * KDIM, lA + j * 32 * BK);
#pragma unroll
    for (int j = 0; j < 4; ++j)
      GLOAD_LDS16(gB + (size_t)j * 32 * KDIM, lB + j * 32 * BK);
    gA += BK;
    gB += BK;
    __syncthreads();   // compiler emits s_waitcnt vmcnt(0) before s_barrier

#pragma unroll
    for (int kk = 0; kk < 2; ++kk) {
      s8v af[4], bf[4];
#pragma unroll
      for (int m = 0; m < 4; ++m)
        af[m] = *(const s8v*)(rA + (m * 16) * BK + kk * 32);
#pragma unroll
      for (int n = 0; n < 4; ++n)
        bf[n] = *(const s8v*)(rB + (n * 16) * BK + kk * 32);
#pragma unroll
      for (int m = 0; m < 4; ++m)
#pragma unroll
        for (int n = 0; n < 4; ++n)
          mfma_16x16x32_bf16(acc[m][n], af[m], bf[n]);
    }
    __syncthreads();
  }

  // Epilogue: C/D layout col = lane&15, row = (lane>>4)*4 + reg.
#pragma unroll
  for (int n = 0; n < 4; ++n) {
    const int col = bcol + wcol + n * 16 + fr;
    const float bv = bias[col];
#pragma unroll
    for (int m = 0; m < 4; ++m) {
      const int row0 = brow + wrow + m * 16 + fq * 4;
#pragma unroll
      for (int j = 0; j < 4; ++j)
        C[(size_t)(row0 + j) * NDIM + col] = acc[m][n][j] + bv;
    }
  }
}

// ---------- launch ----------

extern "C" void kernel_launch(void* const* d_in, const int* in_sizes, int n_in,
                              void* d_out, int out_size, void* d_ws, size_t ws_size,
                              hipStream_t stream) {
  const float* x    = (const float*)d_in[0];
  const float* W    = (const float*)d_in[1];
  const float* bias = (const float*)d_in[2];
  const float* A    = (const float*)d_in[3];
  const float* B    = (const float*)d_in[4];
  float* out = (float*)d_out;

  // Workspace: xb (8192*4096*2 = 64 MiB) + wb (4096*4096*2 = 32 MiB)
  unsigned short* xb = (unsigned short*)d_ws;
  unsigned short* wb = xb + (size_t)M_TOT * KDIM;

  cast_x_kernel<<<2048, 256, 0, stream>>>(x, xb, (M_TOT * KDIM) / 8);
  fuse_w_kernel<<<dim3(KDIM / 1024, NDIM / 64), 256, 0, stream>>>(W, A, B, wb);
  gemm_kernel<<<dim3(NDIM / BN, M_TOT / BM), 256, 0, stream>>>(xb, wb, bias, out);
}

// Round 4
// 496.246 us; speedup vs baseline: 1.1546x; 1.1546x over previous
//
#include <hip/hip_runtime.h>
#include <hip/hip_bf16.h>

// out = x @ (W + B@A)^T + bias, fused:  W' = W + B@A (bf16), xb = bf16(x),
// out = xb @ W'^T + bias (fp32).  M=8192, N=4096, K=4096.
// GEMM: 256x256 8-phase counted-vmcnt template: BK=64, 8 waves (2Mx4N),
// 128 KiB LDS dbuf, both-sides XOR swizzle, vmcnt(4) once per K-tile.
// Stage schedule (deadline-derived, race-free):
//   q0: stage(t+1,A1)  [other buf]      A last read: q2; B last read: q1.
//   q1: stage(t+1,B1)  [other buf]
//   q2: stage(t+2,B0)  [cur buf, >q1 ok]
//   q3: stage(t+2,A0)  [cur buf, >q2 ok]; vmcnt(4)

#define M_TOT 8192
#define NDIM  4096
#define KDIM  4096
#define RANK  16

typedef float f4 __attribute__((ext_vector_type(4)));
typedef short s8v __attribute__((ext_vector_type(8)));   // 8 bf16 payloads

// ---------- helpers ----------

static __device__ __forceinline__ unsigned short f2bf(float f) {
  union { float f; unsigned u; } v; v.f = f;
  unsigned r = v.u + 0x7FFF + ((v.u >> 16) & 1);   // RNE
  return (unsigned short)(r >> 16);
}
static __device__ __forceinline__ unsigned pack2(float lo, float hi) {
  return (unsigned)f2bf(lo) | ((unsigned)f2bf(hi) << 16);
}

static __device__ __forceinline__ void mfma_16x16x32_bf16(f4& d, s8v a, s8v b) {
  asm volatile("v_mfma_f32_16x16x32_bf16 %0, %1, %2, %0"
               : "+v"(d) : "v"(a), "v"(b));
}

#define GLOAD_LDS16(gaddr, laddr)                                              \
  __builtin_amdgcn_global_load_lds(                                            \
      (__attribute__((address_space(1))) void*)(gaddr),                        \
      (__attribute__((address_space(3))) void*)(laddr), 16, 0, 0)

// ---------- kernel 1: cast x fp32 -> bf16 bits, 8 elems/thread ----------

__global__ __launch_bounds__(256) void cast_x_kernel(
    const float* __restrict__ in, unsigned short* __restrict__ out, int n8) {
  int i = blockIdx.x * blockDim.x + threadIdx.x;
  int stride = gridDim.x * blockDim.x;
  for (; i < n8; i += stride) {
    const float4* p = (const float4*)in + (size_t)i * 2;
    float4 a = p[0];
    float4 b = p[1];
    uint4 o;
    o.x = pack2(a.x, a.y);
    o.y = pack2(a.z, a.w);
    o.z = pack2(b.x, b.y);
    o.w = pack2(b.z, b.w);
    ((uint4*)out)[i] = o;
  }
}

// ---------- kernel 2: W' = W + B@A -> bf16. 2048 blocks, 8 o-rows/thread ----

__global__ __launch_bounds__(256) void fuse_w_kernel(
    const float* __restrict__ W, const float* __restrict__ A,
    const float* __restrict__ B, unsigned short* __restrict__ Wb) {
  const int t = threadIdx.x;
  const int i = blockIdx.x * 1024 + t * 4;
  const int o0 = blockIdx.y * 8;

  f4 areg[RANK];
#pragma unroll
  for (int r = 0; r < RANK; ++r)
    areg[r] = *(const f4*)(A + (size_t)r * KDIM + i);

#pragma unroll
  for (int oo = 0; oo < 8; ++oo) {
    const int o = o0 + oo;
    f4 acc = *(const f4*)(W + (size_t)o * KDIM + i);
#pragma unroll
    for (int r = 0; r < RANK; ++r)
      acc += B[o * RANK + r] * areg[r];
    uint2 pk;
    pk.x = pack2(acc.x, acc.y);
    pk.y = pack2(acc.z, acc.w);
    *(uint2*)(Wb + (size_t)o * KDIM + i) = pk;
  }
}

// ---------- kernel 3: 256x256 8-phase bf16 GEMM ----------
// LDS element map (per 32768-elem buffer): A0=0, A1=8192, B0=16384, B1=24576.
// Storage rule (both-sides involution): element (row, colblk cs) lives at
// LDS[row*64 + (cs ^ (row&7))*8]. Staged via linear dest + pre-swizzled
// global source column; read with the same XOR (rule #21).

#define BAR()   __builtin_amdgcn_s_barrier()
#define WAITL() do { asm volatile("s_waitcnt lgkmcnt(0)" ::: "memory");        \
                     __builtin_amdgcn_sched_barrier(0); } while (0)
#define VMC4()  asm volatile("s_waitcnt vmcnt(4)" ::: "memory")
#define PRIO(x) __builtin_amdgcn_s_setprio(x)

__global__ __launch_bounds__(512, 2) void gemm_kernel(
    const unsigned short* __restrict__ Xb,   // [M][K] bf16 bits
    const unsigned short* __restrict__ Wb,   // [N][K] bf16 bits
    const float* __restrict__ bias,
    float* __restrict__ C) {
  __shared__ __attribute__((aligned(16))) unsigned short lds[65536];  // 128 KiB

  const int tid  = threadIdx.x;
  const int w    = tid >> 6;
  const int lane = tid & 63;
  const int fr   = lane & 15;
  const int fq   = lane >> 4;

  // XCD-aware swizzle: nwg=512 = 8 XCDs x 64 contiguous (bijective).
  const unsigned orig = blockIdx.x;
  const unsigned wg   = (orig & 7) * 64 + (orig >> 3);
  const int brow = (int)(wg >> 4) * 256;   // 32 M-tiles
  const int bcol = (int)(wg & 15) * 256;   // 16 N-tiles

  const int wrow = (w >> 2) * 128;   // wave M offset in tile
  const int wcol = (w & 3) * 64;     // wave N offset in tile

  // Read-side swizzle (element units; colblk = 8 elems = 16 B):
  const int swz = (fr & 7) * 8;
  const int ck0 = (fq * 8) ^ swz;          // kk=0 (cs=fq)
  const int ck1 = (fq * 8 + 32) ^ swz;     // kk=1 (cs=fq+4)

  // Staging: thread stages 16 B at linear LDS offset w*512 + lane*8 (+j*4096).
  // Logical row = j*64 + w*8 + (lane>>3); source colblk pre-inverse-swizzled
  // by row&7 = lane>>3.
  const int srow = (w << 3) + (lane >> 3);
  const int sdst = (w << 9) + (lane << 3);
  const int scol = ((lane & 7) ^ (lane >> 3)) << 3;
  const unsigned short* Xs = Xb + (size_t)(brow + srow) * KDIM + scol;
  const unsigned short* Ws = Wb + (size_t)(bcol + srow) * KDIM + scol;

  f4 acc[8][4] = {};
  s8v af[8], bf0[4], bf1[4];

  // reg: 0=A0 (rows 0-127), 1=A1 (128-255), 2=B0, 3=B1
  auto stage = [&](int T, int reg) {
    const int k0 = (T & 63) << 6;   // wrap past K end: valid mem, never read
    const unsigned short* s =
        (reg < 2 ? Xs : Ws) + (size_t)(reg & 1) * 128 * KDIM + k0;
    unsigned short* d = &lds[((T & 1) << 15) + (reg << 13) + sdst];
    GLOAD_LDS16(s, d);
    GLOAD_LDS16(s + 64 * KDIM, d + 4096);
  };

  auto lda = [&](int base, int mh) {
#pragma unroll
    for (int mi = 0; mi < 4; ++mi) {
      const int row = wrow + mh * 64 + mi * 16 + fr;
      af[mi * 2 + 0] = *(const s8v*)&lds[base + row * 64 + ck0];
      af[mi * 2 + 1] = *(const s8v*)&lds[base + row * 64 + ck1];
    }
  };
  auto ldb = [&](s8v* bf, int base, int nh) {
#pragma unroll
    for (int ni = 0; ni < 2; ++ni) {
      const int row = wcol + nh * 32 + ni * 16 + fr;
      bf[ni * 2 + 0] = *(const s8v*)&lds[base + 16384 + row * 64 + ck0];
      bf[ni * 2 + 1] = *(const s8v*)&lds[base + 16384 + row * 64 + ck1];
    }
  };
  auto mm = [&](int mh, int nh, const s8v* bf) {
#pragma unroll
    for (int kk = 0; kk < 2; ++kk)
#pragma unroll
      for (int mi = 0; mi < 4; ++mi)
#pragma unroll
        for (int ni = 0; ni < 2; ++ni)
          mfma_16x16x32_bf16(acc[mh * 4 + mi][nh * 2 + ni],
                             af[mi * 2 + kk], bf[ni * 2 + kk]);
  };

  // Prologue: tile0 complete + tile1's B0,A0 (the T-2 pieces).
  stage(0, 0); stage(0, 2); stage(0, 1); stage(0, 3);
  stage(1, 2); stage(1, 0);
  VMC4();   // tile0's 8 loads complete; tile1's 4 may be in flight
  BAR();

  for (int t = 0; t < 64; ++t) {
    const int base = (t & 1) << 15;
    // q0: read A(mh=0)+B(nh=0); stage next-buf A1
    lda(base, 0); ldb(bf0, base, 0);
    stage(t + 1, 1);
    BAR(); WAITL(); PRIO(1); mm(0, 0, bf0); PRIO(0); BAR();
    // q1: read B(nh=1); stage next-buf B1
    ldb(bf1, base, 1);
    stage(t + 1, 3);
    BAR(); WAITL(); PRIO(1); mm(0, 1, bf1); PRIO(0); BAR();
    // q2: read A(mh=1); stage cur-buf B0 of t+2 (B reads done at q1)
    lda(base, 1);
    stage(t + 2, 2);
    BAR(); WAITL(); PRIO(1); mm(1, 1, bf1); PRIO(0); BAR();
    // q3: stage cur-buf A0 of t+2 (A reads done at q2); counted vmcnt
    stage(t + 2, 0);
    BAR(); WAITL(); PRIO(1); mm(1, 0, bf0); PRIO(0);
    VMC4();
    BAR();
  }

  // Epilogue: C/D layout col = fr, row = fq*4 + reg.
  float bv[4];
#pragma unroll
  for (int n = 0; n < 4; ++n) bv[n] = bias[bcol + wcol + n * 16 + fr];
#pragma unroll
  for (int m = 0; m < 8; ++m) {
#pragma unroll
    for (int jr = 0; jr < 4; ++jr) {
      const int row = brow + wrow + m * 16 + fq * 4 + jr;
      float* cp = C + (size_t)row * NDIM + bcol + wcol + fr;
      cp[0]  = acc[m][0][jr] + bv[0];
      cp[16] = acc[m][1][jr] + bv[1];
      cp[32] = acc[m][2][jr] + bv[2];
      cp[48] = acc[m][3][jr] + bv[3];
    }
  }
}

// ---------- launch ----------

extern "C" void kernel_launch(void* const* d_in, const int* in_sizes, int n_in,
                              void* d_out, int out_size, void* d_ws, size_t ws_size,
                              hipStream_t stream) {
  const float* x    = (const float*)d_in[0];
  const float* W    = (const float*)d_in[1];
  const float* bias = (const float*)d_in[2];
  const float* A    = (const float*)d_in[3];
  const float* B    = (const float*)d_in[4];
  float* out = (float*)d_out;

  unsigned short* xb = (unsigned short*)d_ws;                  // 64 MiB
  unsigned short* wb = xb + (size_t)M_TOT * KDIM;              // 32 MiB

  cast_x_kernel<<<2048, 256, 0, stream>>>(x, xb, (M_TOT * KDIM) / 8);
  fuse_w_kernel<<<dim3(KDIM / 1024, NDIM / 8), 256, 0, stream>>>(W, A, B, wb);
  gemm_kernel<<<512, 512, 0, stream>>>(xb, wb, bias, out);
}